// Round 6
// baseline (75.492 us; speedup 1.0000x reference)
//
#include <hip/hip_runtime.h>
#include <math.h>

// TropConv2D: out[b,ho,wo,f] = max_k(patch + w) - min_k(patch + w) + bias
// B=8, H=W=32, C=32, KH=KW=3, F=64, Ho=Wo=30, K=288. 7200 output pixels.
//
// R8 structural change: k-split with w in REGISTERS; no LDS in main loop.
// Evidence: R4(16 waves/CU)=27.6us, R6/R7(8 waves/CU)=33.5us kernel, VMEM
// vs s_load x made zero difference -> latency/occupancy-bound with the DS
// pipe as top consumer. Old structure coupled 288 ds_read/wave (critical
// path) with 72KiB LDS (occupancy cap). New decomposition removes both:
//  * Block = 256 thr / 4 waves, owns 8 pixels. Wave wv owns k-slice
//    [72wv, 72wv+72): its 72 w-values live in VGPRs (18x float4 groups,
//    loaded once from L2; 72 b32 coalesced loads).
//  * Main loop: 18 j-steps x 8 pixels: wave-uniform x float4 (scalar
//    address via readfirstlane -> s_load; no DS in flight so lgkm mixing
//    is moot) + 4 add + 2 v_max3 + 2 v_min3. ZERO ds ops.
//  * Partials: part[wv][pix][f] float2 in 16 KiB LDS (2-way bank
//    aliasing = free), ONE barrier, wave wv reduces pixels {2wv,2wv+1}
//    (4x ds_read_b64 each, conflict-free), coalesced store.
//  * 900 blocks -> ~3.5 blocks/CU, 14 waves/CU; VGPR ~110 (<128, 4/SIMD).
// k-chunk alignment: slice starts 72wv (≡0 mod 4); 4-aligned chunks never
// cross a 32 (tap) boundary, so each float4 x-load stays within one tap row.

#define TPB 256  // 4 waves
#define CPB 8    // pixels per block
#define KPW 72   // k's per wave (288/4)

__device__ __forceinline__ float fmax3(float a, float b, float c) {
    return fmaxf(fmaxf(a, b), c);
}
__device__ __forceinline__ float fmin3(float a, float b, float c) {
    return fminf(fminf(a, b), c);
}

__global__ __launch_bounds__(TPB, 4) void trop_kernel(
    const float* __restrict__ x,     // (8,32,32,32)
    const float* __restrict__ w,     // (288,64)
    const float* __restrict__ bias,  // (64,)
    float* __restrict__ out)         // (7200,64)
{
    __shared__ float2 part[4][CPB][64];  // 16 KiB

    const int tid  = threadIdx.x;
    const int lane = tid & 63;
    const int wv   = tid >> 6;
    const int K0   = __builtin_amdgcn_readfirstlane(wv * KPW);

    const int pix0 = blockIdx.x * CPB;

    // Load this wave's w-slice into registers: wr[j] = w[K0+4j .. +3][lane].
    // 72 coalesced b32 loads (each: wave reads one 256B row), L2-resident.
    float4 wr[18];
#pragma unroll
    for (int j = 0; j < 18; ++j) {
        const int k = K0 + 4 * j;
        wr[j].x = w[(k + 0) * 64 + lane];
        wr[j].y = w[(k + 1) * 64 + lane];
        wr[j].z = w[(k + 2) * 64 + lane];
        wr[j].w = w[(k + 3) * 64 + lane];
    }

    // Uniform per-pixel x base offsets (SGPR).
    int pbase[CPB];
#pragma unroll
    for (int p = 0; p < CPB; ++p) {
        const int pid = pix0 + p;
        const int wo = pid % 30;
        const int t  = pid / 30;
        const int ho = t % 30;
        const int b  = t / 30;
        pbase[p] = __builtin_amdgcn_readfirstlane((((b * 32 + ho) * 32) + wo) * 32);
    }

    float amax[CPB], amin[CPB];
#pragma unroll
    for (int p = 0; p < CPB; ++p) { amax[p] = -INFINITY; amin[p] = INFINITY; }

#pragma unroll
    for (int j = 0; j < 18; ++j) {
        const int k   = K0 + 4 * j;
        const int tap = k >> 5;       // 0..8
        const int c   = k & 31;       // 0,4,...,28
        const int dy  = tap / 3;
        const int dx  = tap - dy * 3;
        const int xoff = __builtin_amdgcn_readfirstlane((dy * 32 + dx) * 32 + c);
#pragma unroll
        for (int p = 0; p < CPB; ++p) {
            const float4 xv = *(const float4*)(x + pbase[p] + xoff);  // uniform
            const float s0 = xv.x + wr[j].x;
            const float s1 = xv.y + wr[j].y;
            const float s2 = xv.z + wr[j].z;
            const float s3 = xv.w + wr[j].w;
            amax[p] = fmax3(amax[p], fmax3(s0, s1, s2), s3);
            amin[p] = fmin3(amin[p], fmin3(s0, s1, s2), s3);
        }
    }

    // Publish partials: float2 {max, min} per (wave, pixel, filter).
#pragma unroll
    for (int p = 0; p < CPB; ++p)
        part[wv][p][lane] = make_float2(amax[p], amin[p]);

    __syncthreads();  // the only barrier

    // Wave wv reduces pixels {2wv, 2wv+1}: 4 partials each, then store.
    const float bv = bias[lane];
#pragma unroll
    for (int i = 0; i < 2; ++i) {
        const int p = 2 * wv + i;
        const float2 a = part[0][p][lane];
        const float2 b = part[1][p][lane];
        const float2 c = part[2][p][lane];
        const float2 d = part[3][p][lane];
        const float m = fmaxf(fmaxf(a.x, b.x), fmaxf(c.x, d.x));
        const float n = fminf(fminf(a.y, b.y), fminf(c.y, d.y));
        out[(pix0 + p) * 64 + lane] = m - n + bv;
    }
}

extern "C" void kernel_launch(void* const* d_in, const int* in_sizes, int n_in,
                              void* d_out, int out_size, void* d_ws, size_t ws_size,
                              hipStream_t stream) {
    const float* x    = (const float*)d_in[0];
    const float* w    = (const float*)d_in[1];
    const float* bias = (const float*)d_in[2];
    float* out = (float*)d_out;

    // 7200 pixels / 8 per block = 900 blocks; 16 KiB static LDS.
    trop_kernel<<<dim3(900), dim3(TPB), 0, stream>>>(x, w, bias, out);
}

// Round 7
// 67.984 us; speedup vs baseline: 1.1104x; 1.1104x over previous
//
#include <hip/hip_runtime.h>
#include <math.h>

// TropConv2D: out[b,ho,wo,f] = max_k(patch + w) - min_k(patch + w) + bias
// B=8, H=W=32, C=32, KH=KW=3, F=64, Ho=Wo=30, K=288. 7200 output pixels.
//
// R9 = EXACT rerun of R4 (best observed: dur_us 68.1) as a
// reproducibility control. R4..R8 varied structure drastically
// (LDS-heavy vs register-heavy, 8..16 waves/CU, s_load vs VMEM x) and
// all landed 68-76 us while the top-5 dispatches are always the ~40us
// 268MB harness poison-fills. This rerun discriminates:
//   dur ~68  -> R4's structure is genuinely fastest; keep iterating on it.
//   dur ~75  -> the band is harness fill+dispatch overhead; kernel is
//               invisible; declare roofline (harness-bound).
//
// R4 structure: 512-thread blocks (8 waves), wave owns PIX=2 pixels,
// lane = filter. ALL of w (72 KiB) staged to LDS once, ONE barrier,
// x via readfirstlane -> s_load, max3/min3 reassociation.

#define TPB 512  // 8 waves
#define PIX 2

__device__ __forceinline__ float fmax3(float a, float b, float c) {
    return fmaxf(fmaxf(a, b), c);
}
__device__ __forceinline__ float fmin3(float a, float b, float c) {
    return fminf(fminf(a, b), c);
}

__global__ __launch_bounds__(TPB) void trop_kernel(
    const float* __restrict__ x,     // (8,32,32,32)
    const float* __restrict__ w,     // (288,64) = 9 taps * (32,64)
    const float* __restrict__ bias,  // (64,)
    float* __restrict__ out)         // (8,30,30,64) = (7200,64)
{
    extern __shared__ float wlds[];  // 18432 floats = 72 KiB

    const int tid  = threadIdx.x;
    const int lane = tid & 63;
    const int wv   = tid >> 6;

    const int pix0 = blockIdx.x * (8 * PIX) + wv * PIX;  // 0..7198

    // Stage ALL of w: 4608 float4 across 512 threads = 9 each.
    {
        const float4* src = (const float4*)w;
        float4* dst = (float4*)wlds;
#pragma unroll
        for (int i = 0; i < 9; ++i) dst[tid + i * 512] = src[tid + i * 512];
    }

    // Wave-uniform x base offsets (in floats), hoisted to SGPR.
    int xoffp[PIX];
#pragma unroll
    for (int p = 0; p < PIX; ++p) {
        const int pid = pix0 + p;
        const int wo = pid % 30;
        const int t  = pid / 30;
        const int ho = t % 30;
        const int b  = t / 30;
        xoffp[p] = __builtin_amdgcn_readfirstlane((((b * 32 + ho) * 32) + wo) * 32);
    }

    float amax[PIX], amin[PIX];
#pragma unroll
    for (int p = 0; p < PIX; ++p) { amax[p] = -INFINITY; amin[p] = INFINITY; }

    __syncthreads();  // the only barrier

#pragma unroll
    for (int tap = 0; tap < 9; ++tap) {
        const int dy = tap / 3;
        const int dx = tap % 3;
        const int xoff = (dy * 32 + dx) * 32;
        const float* wl = wlds + tap * 2048;
#pragma unroll
        for (int c = 0; c < 32; c += 4) {
            const float w0 = wl[(c + 0) * 64 + lane];
            const float w1 = wl[(c + 1) * 64 + lane];
            const float w2 = wl[(c + 2) * 64 + lane];
            const float w3 = wl[(c + 3) * 64 + lane];
#pragma unroll
            for (int p = 0; p < PIX; ++p) {
                const float* xb = x + xoffp[p] + xoff;  // scalar (SGPR) address
                const float s0 = xb[c + 0] + w0;
                const float s1 = xb[c + 1] + w1;
                const float s2 = xb[c + 2] + w2;
                const float s3 = xb[c + 3] + w3;
                amax[p] = fmax3(amax[p], fmax3(s0, s1, s2), s3);
                amin[p] = fmin3(amin[p], fmin3(s0, s1, s2), s3);
            }
        }
    }

    const float bv = bias[lane];
#pragma unroll
    for (int p = 0; p < PIX; ++p)
        out[(pix0 + p) * 64 + lane] = amax[p] - amin[p] + bv;
}

extern "C" void kernel_launch(void* const* d_in, const int* in_sizes, int n_in,
                              void* d_out, int out_size, void* d_ws, size_t ws_size,
                              hipStream_t stream) {
    const float* x    = (const float*)d_in[0];
    const float* w    = (const float*)d_in[1];
    const float* bias = (const float*)d_in[2];
    float* out = (float*)d_out;

    // Allow 72 KiB dynamic LDS (gfx950 has 160 KiB/CU).
    static int attr_done = 0;
    if (!attr_done) {
        (void)hipFuncSetAttribute((const void*)trop_kernel,
                                  hipFuncAttributeMaxDynamicSharedMemorySize,
                                  73728);
        attr_done = 1;
    }

    // 7200 pixels / (8 waves * 2 pixels) = 450 blocks
    trop_kernel<<<dim3(450), dim3(TPB), 73728, stream>>>(x, w, bias, out);
}